// Round 10
// baseline (319.225 us; speedup 1.0000x reference)
//
#include <hip/hip_runtime.h>

// OT_GNN: 2x GCN -> per-node fused-GW distance to 10 templates -> linear head.
// R19: W1 -> LDS. R18 falsified the x-pattern theory (x fully LDS-staged,
// still 110us). Post-mortem arithmetic: the shared structure of ALL gemm1
// variants is per-wave streaming of W1 (64KB = 2x L1 -> thrash, ~200cy L2
// per k-batch; 105cy/batch vs 22cy VALU issue => VALUBusy 21% — matches the
// measured 22% exactly). Fix: stage W1 into LDS once per block (dense 16B
// chunks, L2/L3-hot source), inner loop reads w via conflict-free dense
// ds_read_u16. LDS 80KB -> 2 blocks/CU. VALU floor ~23us.
// Predicted: gemm1 110 -> 40-60us, VALUBusy -> 45-65%. Falsifier >=90us =>
// gemm1 genuinely floored -> pivot to gathers/fgw (~195us unprofiled).
// Certificate (R4): K = exp(-5(M+tens)) == 0 exactly in fp32 when
// (sqrt(tn2min)-sqrt(xn2max))^2 >= 26, since tens >= -2 => dist == 0 exact.

#define NN   20000
#define EE   320000
#define FIN  512
#define HID  64
#define KNEI 8
#define LSZ  9      // K_NEI + 1
#define NTPL 10
#define NTN  8
#define NCLS 6
#define CAP  48     // bucket capacity per node (max in-degree ~34)
#define GR   16     // gemm1 rows staged per block

typedef unsigned short bf16_t;
typedef unsigned short us8 __attribute__((ext_vector_type(8)));

__device__ __forceinline__ float b2f(bf16_t u) {
  union { unsigned int i; float f; } v; v.i = ((unsigned int)u) << 16; return v.f;
}
__device__ __forceinline__ bf16_t f2b(float f) {
  union { float f; unsigned int i; } v; v.f = f;
  unsigned int x = v.i;
  return (bf16_t)((x + 0x7fffu + ((x >> 16) & 1u)) >> 16);  // RNE
}
__device__ __forceinline__ float ldf(const void* p, long i, int fp32) {
  return fp32 ? ((const float*)p)[i] : b2f(((const bf16_t*)p)[i]);
}
__device__ __forceinline__ int ldi(const void* p, long i, int i64) {
  return i64 ? (int)((const long long*)p)[i] : ((const int*)p)[i];
}
__device__ __forceinline__ float frcp(float x) { return __builtin_amdgcn_rcpf(x); }

// ---------- dtype probe + template row-norm mins + pos zeroing ----------
// grid 79 x 256: every block zeroes a stripe of pos; block 0 also probes.
__global__ __launch_bounds__(256) void probe_kernel(const void* __restrict__ x,
                                                    const void* __restrict__ ei,
                                                    const void* __restrict__ tfeat,
                                                    int* __restrict__ flags,
                                                    float* __restrict__ tn2min,
                                                    int* __restrict__ pos) {
  int tid = threadIdx.x;
  int zi = blockIdx.x * 256 + tid;
  if (zi < NN) pos[zi] = 0;
  if (blockIdx.x != 0) return;

  __shared__ int sfl[2];
  __shared__ float tn2s[80];
  if (tid == 0) {
    int sane = 0;
    for (int k = 0; k < 64; k += 2) {
      bf16_t u = ((const bf16_t*)x)[k];
      int e = (u >> 7) & 0xff;
      if (e >= 112 && e <= 142) sane++;
    }
    int f0 = (sane < 24) ? 1 : 0;
    int zc = 0;
    for (int k = 1; k < 64; k += 2)
      if (((const int*)ei)[k] == 0) zc++;
    int f1 = (zc >= 16) ? 1 : 0;
    flags[0] = f0; flags[1] = f1;
    sfl[0] = f0; sfl[1] = f1;
  }
  __syncthreads();
  if (tid < 80) {
    int fF = sfl[0];
    float s = 0.f;
    for (int k = 0; k < HID; ++k) {
      float v = ldf(tfeat, (long)tid * HID + k, fF);
      s += v * v;
    }
    tn2s[tid] = s;
  }
  __syncthreads();
  if (tid == 0) {
    float gmin = 1e30f;
    for (int t = 0; t < NTPL; ++t) {
      float m = tn2s[t * 8];
      for (int r = 1; r < 8; ++r) m = fminf(m, tn2s[t * 8 + r]);
      tn2min[t] = m;
      gmin = fminf(gmin, m);
    }
    tn2min[NTPL] = gmin;
  }
}

// ---------- bucket scatter: pos becomes in-degree, slot16 holds sources ----
__global__ __launch_bounds__(256) void scatter_kernel(const void* __restrict__ ei,
                                                      int* __restrict__ pos,
                                                      unsigned short* __restrict__ slot,
                                                      const int* __restrict__ flags) {
  int i = blockIdx.x * 256 + threadIdx.x;
  if (i >= EE) return;
  int i64 = flags[1];
  int s = ldi(ei, i, i64);
  int d = ldi(ei, (long)EE + i, i64);
  int p = atomicAdd(&pos[d], 1);
  if (p < CAP) slot[(long)d * CAP + p] = (unsigned short)s;
}

// ---------- GEMM1: sxw1 = (x @ W1) * dinv ----------
// bf16 path: W1 (64KB) AND a 16-row x tile staged into LDS with lane-dense
// 16B chunks. Inner loop reads w via dense conflict-free ds_read (short,
// hideable latency) instead of L1-thrashing per-wave global W1 streams —
// the measured 110us floor (VALUBusy 22% == 22cy VALU / 105cy L2-latency
// per k-batch). x rows via LDS broadcast as in R18.
__global__ __launch_bounds__(256) void gemm1_kernel(const void* __restrict__ x,
                                                    const void* __restrict__ W1,
                                                    const int* __restrict__ cnt,
                                                    float* __restrict__ xw1,
                                                    const int* __restrict__ flags) {
  const int tid = threadIdx.x;
  const int wid = tid >> 6;
  const int lane = tid & 63;

  if (!flags[0]) {
    __shared__ bf16_t ws1[FIN * HID];   // 64 KB, [k][c] row-major (as source)
    __shared__ bf16_t xs[GR][FIN];      // 16 KB
    const bf16_t* wp = (const bf16_t*)W1;
    // stage W1: 32768 bf16 = 4096 16B-chunks; 256 threads x 16 iters, dense
#pragma unroll
    for (int it = 0; it < (FIN * HID / 8) / 256; ++it) {
      int c = it * 256 + tid;
      *(us8*)&ws1[c * 8] = *(const us8*)(wp + c * 8);
    }
    const bf16_t* xb = (const bf16_t*)x + (long)blockIdx.x * GR * FIN;
#pragma unroll
    for (int it = 0; it < (GR * FIN / 8) / 256; ++it) {   // 4 iters
      int c = it * 256 + tid;           // 16B chunk id; 64 chunks per row
      int r = c >> 6, cc = (c & 63) * 8;
      *(us8*)&xs[r][cc] = *(const us8*)(xb + r * FIN + cc);
    }
    __syncthreads();

    const int row0 = wid * 4;           // rows within the staged tile
    const int grow0 = blockIdx.x * GR + row0;
    float a0 = 0.f, a1 = 0.f, a2 = 0.f, a3 = 0.f;
#pragma unroll 2
    for (int k8 = 0; k8 < FIN / 8; ++k8) {
      us8 r0 = *(const us8*)&xs[row0 + 0][k8 * 8];
      us8 r1 = *(const us8*)&xs[row0 + 1][k8 * 8];
      us8 r2 = *(const us8*)&xs[row0 + 2][k8 * 8];
      us8 r3 = *(const us8*)&xs[row0 + 3][k8 * 8];
#pragma unroll
      for (int q = 0; q < 8; ++q) {
        float w = b2f(ws1[(k8 * 8 + q) * HID + lane]);   // dense, bank-free
        a0 += b2f(r0[q]) * w;
        a1 += b2f(r1[q]) * w;
        a2 += b2f(r2[q]) * w;
        a3 += b2f(r3[q]) * w;
      }
    }
    float d0 = rsqrtf((float)cnt[grow0 + 0] + 1.0f);
    float d1 = rsqrtf((float)cnt[grow0 + 1] + 1.0f);
    float d2 = rsqrtf((float)cnt[grow0 + 2] + 1.0f);
    float d3 = rsqrtf((float)cnt[grow0 + 3] + 1.0f);
    xw1[(long)(grow0 + 0) * HID + lane] = a0 * d0;
    xw1[(long)(grow0 + 1) * HID + lane] = a1 * d1;
    xw1[(long)(grow0 + 2) * HID + lane] = a2 * d2;
    xw1[(long)(grow0 + 3) * HID + lane] = a3 * d3;
  } else {
    // ---- fp32 fallback: R5 scalar form, direct global
    int row0 = blockIdx.x * GR + wid * 4;
    if (row0 >= NN) return;
    float a0 = 0.f, a1 = 0.f, a2 = 0.f, a3 = 0.f;
    const float* x0 = (const float*)x + (long)row0 * FIN;
    const float* wp = (const float*)W1;
#pragma unroll 8
    for (int k = 0; k < FIN; ++k) {
      float w = wp[k * HID + lane];
      a0 += x0[k] * w;
      a1 += x0[FIN + k] * w;
      a2 += x0[2 * FIN + k] * w;
      a3 += x0[3 * FIN + k] * w;
    }
    float d0 = rsqrtf((float)cnt[row0 + 0] + 1.0f);
    float d1 = rsqrtf((float)cnt[row0 + 1] + 1.0f);
    float d2 = rsqrtf((float)cnt[row0 + 2] + 1.0f);
    float d3 = rsqrtf((float)cnt[row0 + 3] + 1.0f);
    xw1[(long)(row0 + 0) * HID + lane] = a0 * d0;
    xw1[(long)(row0 + 1) * HID + lane] = a1 * d1;
    xw1[(long)(row0 + 2) * HID + lane] = a2 * d2;
    xw1[(long)(row0 + 3) * HID + lane] = a3 * d3;
  }
}

// ---------- gather A: h1 = relu(Agg(sxw1)+b1); sxw2 = (h1 @ W2)*dinv -------
__global__ __launch_bounds__(256) void gatherA_kernel(const float* __restrict__ sxw,
                                                      const int* __restrict__ cnt,
                                                      const unsigned short* __restrict__ slot,
                                                      float* __restrict__ sxw2,
                                                      const void* __restrict__ b1v,
                                                      const void* __restrict__ W2,
                                                      const int* __restrict__ flags) {
  int n = blockIdx.x * 4 + (threadIdx.x >> 6);
  if (n >= NN) return;
  int fF = flags[0];
  int c = threadIdx.x & 63;
  float acc = sxw[(long)n * HID + c];           // self term (already * dinv[n])
  int m = cnt[n]; if (m > CAP) m = CAP;
  const unsigned short* sl = slot + (long)n * CAP;
  float accB = 0.f;
  for (int e0 = 0; e0 < m; e0 += 8) {
    us8 s8 = *(const us8*)(sl + e0);            // 8 ids, 16B
    if (e0 + 0 < m) acc  += sxw[(long)s8[0] * HID + c];
    if (e0 + 1 < m) accB += sxw[(long)s8[1] * HID + c];
    if (e0 + 2 < m) acc  += sxw[(long)s8[2] * HID + c];
    if (e0 + 3 < m) accB += sxw[(long)s8[3] * HID + c];
    if (e0 + 4 < m) acc  += sxw[(long)s8[4] * HID + c];
    if (e0 + 5 < m) accB += sxw[(long)s8[5] * HID + c];
    if (e0 + 6 < m) acc  += sxw[(long)s8[6] * HID + c];
    if (e0 + 7 < m) accB += sxw[(long)s8[7] * HID + c];
  }
  float dn = rsqrtf((float)cnt[n] + 1.0f);
  float h1 = (acc + accB) * dn + ldf(b1v, c, fF);
  h1 = h1 > 0.f ? h1 : 0.f;                     // relu'd hidden, channel c

  // xw2[n][c] = sum_k h1[k] * W2[k][c]  via 64 wave broadcasts; fold dinv[n]
  float o = 0.f;
#pragma unroll 8
  for (int k = 0; k < HID; ++k)
    o += __shfl(h1, k) * ldf(W2, k * HID + c, fF);
  sxw2[(long)n * HID + c] = o * dn;
}

// ---------- gather B: h2 = Agg(sxw2); n2 = ||h2+b2||^2 ----------
__global__ __launch_bounds__(256) void gatherB_kernel(const float* __restrict__ sxw,
                                                      const int* __restrict__ cnt,
                                                      const unsigned short* __restrict__ slot,
                                                      float* __restrict__ h,
                                                      float* __restrict__ n2,
                                                      const void* __restrict__ b2v,
                                                      const int* __restrict__ flags) {
  int n = blockIdx.x * 4 + (threadIdx.x >> 6);
  if (n >= NN) return;
  int c = threadIdx.x & 63;
  float acc = sxw[(long)n * HID + c];           // self term (already * dinv[n])
  int m = cnt[n]; if (m > CAP) m = CAP;
  const unsigned short* sl = slot + (long)n * CAP;
  float accB = 0.f;
  for (int e0 = 0; e0 < m; e0 += 8) {
    us8 s8 = *(const us8*)(sl + e0);
    if (e0 + 0 < m) acc  += sxw[(long)s8[0] * HID + c];
    if (e0 + 1 < m) accB += sxw[(long)s8[1] * HID + c];
    if (e0 + 2 < m) acc  += sxw[(long)s8[2] * HID + c];
    if (e0 + 3 < m) accB += sxw[(long)s8[3] * HID + c];
    if (e0 + 4 < m) acc  += sxw[(long)s8[4] * HID + c];
    if (e0 + 5 < m) accB += sxw[(long)s8[5] * HID + c];
    if (e0 + 6 < m) acc  += sxw[(long)s8[6] * HID + c];
    if (e0 + 7 < m) accB += sxw[(long)s8[7] * HID + c];
  }
  float dn = rsqrtf((float)cnt[n] + 1.0f);
  float h2 = (acc + accB) * dn;
  h[(long)n * HID + c] = h2;
  float v = h2 + ldf(b2v, c, flags[0]);
  float s = v * v;
  s += __shfl_xor(s, 1); s += __shfl_xor(s, 2); s += __shfl_xor(s, 4);
  s += __shfl_xor(s, 8); s += __shfl_xor(s, 16); s += __shfl_xor(s, 32);
  if (c == 0) n2[n] = s;
}

// ---------- FGW: 4 nodes/block, 8-lane octet per (node, template) ----------
#define NODES_PB 4
#define TPN 80            // threads per node (10 templates x 8 lanes)
#define XLP 65            // padded xl row stride

__global__ __launch_bounds__(320, 2) void fgw_kernel(
    const float* __restrict__ h2,        // [NN,64] fp32 ws (pre-b2)
    const void* __restrict__ b2v,
    const void* __restrict__ nbr_idx,
    const void* __restrict__ nbr_mask,
    const void* __restrict__ C_local,
    const void* __restrict__ tmpl,       // [10,8,8]
    const void* __restrict__ tfeat,      // [10,8,64]
    const void* __restrict__ Wlin,       // [74,6]
    const void* __restrict__ blin,       // [6]
    void* __restrict__ out,              // [NN,6]
    const int* __restrict__ flags,
    const float* __restrict__ tn2min,    // [11]: per-t mins + global min
    const float* __restrict__ n2)        // [NN] node norm^2
{
  const int tid = threadIdx.x;
  const int fF = flags[0];
  const int fI = flags[1];
  const int nb = tid / TPN;
  const int local = tid - nb * TPN;      // [0,80)
  const int t = local >> 3;
  const int j = local & 7;
  const int n = blockIdx.x * NODES_PB + nb;
  const int lane = tid & 63;
  const int ob = lane & 56;

  __shared__ float xlS[NODES_PB][LSZ][XLP];
  __shared__ float C1S[NODES_PB][81];
  __shared__ float hwS[NODES_PB][LSZ];
  __shared__ float f1S[NODES_PB][LSZ];
  __shared__ float xnS[NODES_PB][LSZ];
  __shared__ float distS[NODES_PB][NTPL];
  __shared__ float xmaxS[NODES_PB];
  __shared__ int   needS[NODES_PB];
  __shared__ int   sidxS[NODES_PB][LSZ];
  __shared__ float WlinS[(HID + NTPL) * NCLS + NCLS];   // Wlin + blin

  // stage epilogue weights once per block (coalesced-ish)
  for (int i = tid; i < (HID + NTPL) * NCLS; i += 320)
    WlinS[i] = ldf(Wlin, i, fF);
  if (tid < NCLS) WlinS[(HID + NTPL) * NCLS + tid] = ldf(blin, tid, fF);

  if (local < LSZ) {
    int idx = (local == 0) ? n : ldi(nbr_idx, (long)n * KNEI + local - 1, fI);
    sidxS[nb][local] = idx;
    xnS[nb][local] = n2[idx];
  }
  if (local < HID)
    xlS[nb][0][local] = h2[(long)n * HID + local] + ldf(b2v, local, fF);
  __syncthreads();   // B1

  if (local == 0) {
    float xm = xnS[nb][0];
#pragma unroll
    for (int l = 1; l < LSZ; ++l) xm = fmaxf(xm, xnS[nb][l]);
    xmaxS[nb] = xm;
    needS[nb] = ((sqrtf(tn2min[NTPL]) - sqrtf(xm)) >= 5.0990195f) ? 0 : 1;
  }
  __syncthreads();   // B2

  const int need = needS[nb];
  if (need) {
    for (int i = local; i < 8 * HID; i += TPN) {
      int l = 1 + (i >> 6), k = i & 63;
      xlS[nb][l][k] = h2[(long)sidxS[nb][l] * HID + k] + ldf(b2v, k, fF);
    }
    for (int i = local; i < 81; i += TPN)
      C1S[nb][i] = ldf(C_local, (long)n * 81 + i, fF);
  }
  __syncthreads();   // B3

  if (need && local < LSZ) {
    int l = local;
    float msum = 0.f, f1 = 0.f;
#pragma unroll
    for (int jj = 0; jj < LSZ; ++jj) {
      float mj = ldf(nbr_mask, (long)n * LSZ + jj, fF);
      msum += mj;
      float c = C1S[nb][l * LSZ + jj];
      f1 += c * c * mj;
    }
    float inv = frcp(msum);
    hwS[nb][l] = ldf(nbr_mask, (long)n * LSZ + l, fF) * inv;
    f1S[nb][l] = f1 * inv;
  }
  __syncthreads();   // B4

  bool slow = need && ((sqrtf(tn2min[t]) - sqrtf(xmaxS[nb])) < 5.0990195f);
  if (slow) {
    float C2c[NTN];
    float f2h2;
    {
      float s = 0.f;
#pragma unroll
      for (int m = 0; m < NTN; ++m) {
        C2c[m] = ldf(tmpl, t * 64 + m * 8 + j, fF);
        float r = ldf(tmpl, t * 64 + j * 8 + m, fF);
        s += r * r;
      }
      f2h2 = s * 0.125f;
    }
    float hwr[LSZ], f1r[LSZ];
#pragma unroll
    for (int l = 0; l < LSZ; ++l) { hwr[l] = hwS[nb][l]; f1r[l] = f1S[nb][l]; }

    float Mc[LSZ];
    {
      float accI[LSZ];
#pragma unroll
      for (int l = 0; l < LSZ; ++l) accI[l] = 0.f;
      float tn2 = 0.f;
      const long tb = (long)local * HID;
      for (int kb = 0; kb < 8; ++kb) {
        float r[8];
#pragma unroll
        for (int q = 0; q < 8; ++q) r[q] = ldf(tfeat, tb + kb * 8 + q, fF);
#pragma unroll
        for (int q = 0; q < 8; ++q) tn2 += r[q] * r[q];
#pragma unroll
        for (int l = 0; l < LSZ; ++l) {
          float s = 0.f;
#pragma unroll
          for (int q = 0; q < 8; ++q) s += xlS[nb][l][kb * 8 + q] * r[q];
          accI[l] += s;
        }
      }
#pragma unroll
      for (int l = 0; l < LSZ; ++l)
        Mc[l] = xnS[nb][l] + tn2 - 2.f * accI[l];
    }

    float Tc[LSZ], Kc[LSZ], u[LSZ];
#pragma unroll
    for (int l = 0; l < LSZ; ++l) Tc[l] = hwr[l] * 0.125f;

    float v = 1.0f;
    for (int outer = 0; outer < 3; ++outer) {
      float Ac[LSZ];
#pragma unroll
      for (int l = 0; l < LSZ; ++l) {
        float s = 0.f;
#pragma unroll
        for (int l2 = 0; l2 < LSZ; ++l2) s += C1S[nb][l * LSZ + l2] * Tc[l2];
        Ac[l] = s;
      }
#pragma unroll
      for (int l = 0; l < LSZ; ++l) {
        float s = 0.f;
#pragma unroll
        for (int m = 0; m < NTN; ++m) s += __shfl(Ac[l], ob + m) * C2c[m];
        float tens = f1r[l] + f2h2 - 2.f * s;
        Kc[l] = __expf(-5.0f * (Mc[l] + tens));
      }
      v = 1.0f;
      for (int it = 0; it < 5; ++it) {
#pragma unroll
        for (int l = 0; l < LSZ; ++l) {
          float p = Kc[l] * v;
          p += __shfl_xor(p, 1); p += __shfl_xor(p, 2); p += __shfl_xor(p, 4);
          u[l] = hwr[l] * frcp(p + 1e-16f);
        }
        float s = 0.f;
#pragma unroll
        for (int l = 0; l < LSZ; ++l) s += Kc[l] * u[l];
        v = 0.125f * frcp(s + 1e-16f);
      }
#pragma unroll
      for (int l = 0; l < LSZ; ++l) Tc[l] = u[l] * Kc[l] * v;
    }
    {
      float Ac[LSZ];
#pragma unroll
      for (int l = 0; l < LSZ; ++l) {
        float s = 0.f;
#pragma unroll
        for (int l2 = 0; l2 < LSZ; ++l2) s += C1S[nb][l * LSZ + l2] * Tc[l2];
        Ac[l] = s;
      }
      float cl = 0.f;
#pragma unroll
      for (int l = 0; l < LSZ; ++l) {
        float s = 0.f;
#pragma unroll
        for (int m = 0; m < NTN; ++m) s += __shfl(Ac[l], ob + m) * C2c[m];
        float tens = f1r[l] + f2h2 - 2.f * s;
        cl += Tc[l] * 0.5f * (Mc[l] + tens);
      }
      cl += __shfl_xor(cl, 1); cl += __shfl_xor(cl, 2); cl += __shfl_xor(cl, 4);
      if (j == 0) distS[nb][t] = cl;
    }
  } else if (j == 0) {
    distS[nb][t] = 0.f;
  }
  __syncthreads();   // B5

  if (local < NCLS) {
    int c = local;
    float acc = WlinS[(HID + NTPL) * NCLS + c];
#pragma unroll
    for (int k = 0; k < HID; ++k)
      acc += xlS[nb][0][k] * WlinS[k * NCLS + c];
#pragma unroll
    for (int tt = 0; tt < NTPL; ++tt)
      acc += distS[nb][tt] * WlinS[(HID + tt) * NCLS + c];
    float r = acc > 0.f ? acc : 0.f;
    if (fF) ((float*)out)[(long)n * NCLS + c] = r;
    else    ((bf16_t*)out)[(long)n * NCLS + c] = f2b(r);
  }
}

extern "C" void kernel_launch(void* const* d_in, const int* in_sizes, int n_in,
                              void* d_out, int out_size, void* d_ws, size_t ws_size,
                              hipStream_t stream) {
  (void)in_sizes; (void)n_in; (void)out_size; (void)ws_size;
  const void* x     = d_in[0];
  const void* ei    = d_in[1];
  const void* nbr   = d_in[2];
  const void* nmask = d_in[3];
  const void* Cl    = d_in[4];
  const void* W1    = d_in[5];
  const void* b1    = d_in[6];
  const void* W2    = d_in[7];
  const void* b2    = d_in[8];
  const void* tmpl  = d_in[9];
  const void* tfeat = d_in[10];
  const void* Wlin  = d_in[11];
  const void* blin  = d_in[12];

  // ws layout (4B words): flags[4] | tn2min[12] | n2 NN | pos NN |
  //   slot16 (CAP*NN/2 words) | bufA 64NN | bufB 64NN
  int*            flags  = (int*)d_ws;
  float*          tn2min = (float*)d_ws + 4;
  float*          n2     = (float*)d_ws + 16;
  int*            pos    = (int*)(n2 + NN);
  unsigned short* slot   = (unsigned short*)(pos + NN);
  float*          bufA   = (float*)((int*)(pos + NN) + (long)CAP * NN / 2);
  float*          bufB   = bufA + (long)NN * HID;

  // probe + pos zeroing (79 blocks cover NN; block 0 probes)
  probe_kernel<<<79, 256, 0, stream>>>(x, ei, tfeat, flags, tn2min, pos);
  scatter_kernel<<<(EE + 255) / 256, 256, 0, stream>>>(ei, pos, slot, flags);

  // layer 1 GEMM: W1 + x tile both LDS-staged; R5 compute; dinv fold
  gemm1_kernel<<<NN / GR, 256, 0, stream>>>(x, W1, pos, bufA, flags);
  // gather A: sum sxw1 rows -> relu(h1) -> in-wave GEMV W2 -> sxw2 (bufB)
  gatherA_kernel<<<NN / 4, 256, 0, stream>>>(bufA, pos, slot, bufB, b1, W2, flags);
  // gather B: sum sxw2 rows -> h2 (bufA) + n2
  gatherB_kernel<<<NN / 4, 256, 0, stream>>>(bufB, pos, slot, bufA, n2, b2, flags);

  fgw_kernel<<<NN / NODES_PB, 320, 0, stream>>>(bufA, b2, nbr, nmask, Cl, tmpl,
                                                tfeat, Wlin, blin, d_out, flags,
                                                tn2min, n2);
}

// Round 11
// 300.975 us; speedup vs baseline: 1.0606x; 1.0606x over previous
//
#include <hip/hip_runtime.h>

// OT_GNN: 2x GCN -> per-node fused-GW distance to 10 templates -> linear head.
// R20: pivot off gemm1 (6 theories falsified: scalar/MFMA-global/MFMA-LDS/
// x-staged/split/W1-staged all 108-128us; L3-hot x doesn't help; VALUBusy
// pinned ~20% regardless). gemm1 reverted to R5 form (best known, 110us).
// This round attacks the ~195us spread over the other kernels (each <43us,
// masked by harness fills): (1) slot pre-filled with sentinel NN + phantom
// zero row sxw[NN] -> gather loops become UNCONDITIONAL 8-wide batches (no
// branches, full MLP); (2) fgw tfeat loads vectorized us8 (was 64 scalar
// bf16 loads/thread); (3) probe absorbs slot-fill + zero-row init.
// Falsifier: total >= 300us => gathers share gemm1's floor; next round is
// the bf16-intermediate gamble or roofline declaration.
// Certificate (R4): K = exp(-5(M+tens)) == 0 exactly in fp32 when
// (sqrt(tn2min)-sqrt(xn2max))^2 >= 26, since tens >= -2 => dist == 0 exact.

#define NN   20000
#define EE   320000
#define FIN  512
#define HID  64
#define KNEI 8
#define LSZ  9      // K_NEI + 1
#define NTPL 10
#define NTN  8
#define NCLS 6
#define CAP  48     // bucket capacity per node (max in-degree ~34)

typedef unsigned short bf16_t;
typedef unsigned short us8 __attribute__((ext_vector_type(8)));

__device__ __forceinline__ float b2f(bf16_t u) {
  union { unsigned int i; float f; } v; v.i = ((unsigned int)u) << 16; return v.f;
}
__device__ __forceinline__ bf16_t f2b(float f) {
  union { float f; unsigned int i; } v; v.f = f;
  unsigned int x = v.i;
  return (bf16_t)((x + 0x7fffu + ((x >> 16) & 1u)) >> 16);  // RNE
}
__device__ __forceinline__ float ldf(const void* p, long i, int fp32) {
  return fp32 ? ((const float*)p)[i] : b2f(((const bf16_t*)p)[i]);
}
__device__ __forceinline__ int ldi(const void* p, long i, int i64) {
  return i64 ? (int)((const long long*)p)[i] : ((const int*)p)[i];
}
__device__ __forceinline__ float frcp(float x) { return __builtin_amdgcn_rcpf(x); }

// ---------- probe + pos zeroing + slot sentinel fill + phantom zero rows ----
// grid 512 x 256. Every thread: zero a pos entry, fill a us8 chunk of slot
// with sentinel NN. Block 1/2: zero phantom rows bufA[NN], bufB[NN].
// Block 0: dtype flags + template row-norm mins.
__global__ __launch_bounds__(256) void probe_kernel(const void* __restrict__ x,
                                                    const void* __restrict__ ei,
                                                    const void* __restrict__ tfeat,
                                                    int* __restrict__ flags,
                                                    float* __restrict__ tn2min,
                                                    int* __restrict__ pos,
                                                    unsigned short* __restrict__ slot,
                                                    float* __restrict__ bufA,
                                                    float* __restrict__ bufB) {
  int tid = threadIdx.x;
  long gid = (long)blockIdx.x * 256 + tid;
  if (gid < NN) pos[gid] = 0;
  if (gid < (long)CAP * NN / 8) {
    us8 v;
#pragma unroll
    for (int q = 0; q < 8; ++q) v[q] = (unsigned short)NN;
    ((us8*)slot)[gid] = v;
  }
  if (blockIdx.x == 1 && tid < HID) bufA[(long)NN * HID + tid] = 0.f;
  if (blockIdx.x == 2 && tid < HID) bufB[(long)NN * HID + tid] = 0.f;
  if (blockIdx.x != 0) return;

  __shared__ int sfl[2];
  __shared__ float tn2s[80];
  if (tid == 0) {
    int sane = 0;
    for (int k = 0; k < 64; k += 2) {
      bf16_t u = ((const bf16_t*)x)[k];
      int e = (u >> 7) & 0xff;
      if (e >= 112 && e <= 142) sane++;
    }
    int f0 = (sane < 24) ? 1 : 0;
    int zc = 0;
    for (int k = 1; k < 64; k += 2)
      if (((const int*)ei)[k] == 0) zc++;
    int f1 = (zc >= 16) ? 1 : 0;
    flags[0] = f0; flags[1] = f1;
    sfl[0] = f0; sfl[1] = f1;
  }
  __syncthreads();
  if (tid < 80) {
    int fF = sfl[0];
    float s = 0.f;
    for (int k = 0; k < HID; ++k) {
      float v = ldf(tfeat, (long)tid * HID + k, fF);
      s += v * v;
    }
    tn2s[tid] = s;
  }
  __syncthreads();
  if (tid == 0) {
    float gmin = 1e30f;
    for (int t = 0; t < NTPL; ++t) {
      float m = tn2s[t * 8];
      for (int r = 1; r < 8; ++r) m = fminf(m, tn2s[t * 8 + r]);
      tn2min[t] = m;
      gmin = fminf(gmin, m);
    }
    tn2min[NTPL] = gmin;
  }
}

// ---------- bucket scatter: pos becomes in-degree, slot16 holds sources ----
__global__ __launch_bounds__(256) void scatter_kernel(const void* __restrict__ ei,
                                                      int* __restrict__ pos,
                                                      unsigned short* __restrict__ slot,
                                                      const int* __restrict__ flags) {
  int i = blockIdx.x * 256 + threadIdx.x;
  if (i >= EE) return;
  int i64 = flags[1];
  int s = ldi(ei, i, i64);
  int d = ldi(ei, (long)EE + i, i64);
  int p = atomicAdd(&pos[d], 1);
  if (p < CAP) slot[(long)d * CAP + p] = (unsigned short)s;
}

// ---------- GEMM1 (scalar, R5 form) + dinv fold: sxw1 = (x @ W1) * dinv ----
__global__ __launch_bounds__(256) void gemm1_kernel(const void* __restrict__ x,
                                                    const void* __restrict__ W1,
                                                    const int* __restrict__ cnt,
                                                    float* __restrict__ xw1,
                                                    const int* __restrict__ flags) {
  int wave = blockIdx.x * 4 + (threadIdx.x >> 6);
  int lane = threadIdx.x & 63;
  int row0 = wave * 4;
  if (row0 >= NN) return;
  float a0 = 0.f, a1 = 0.f, a2 = 0.f, a3 = 0.f;
  if (!flags[0]) {
    const bf16_t* xb = (const bf16_t*)x + (long)row0 * FIN;
    const bf16_t* wp = (const bf16_t*)W1;
#pragma unroll 2
    for (int k8 = 0; k8 < FIN / 8; ++k8) {
      us8 r0 = *(const us8*)(xb + k8 * 8);
      us8 r1 = *(const us8*)(xb + FIN + k8 * 8);
      us8 r2 = *(const us8*)(xb + 2 * FIN + k8 * 8);
      us8 r3 = *(const us8*)(xb + 3 * FIN + k8 * 8);
#pragma unroll
      for (int q = 0; q < 8; ++q) {
        float w = b2f(wp[(k8 * 8 + q) * HID + lane]);
        a0 += b2f(r0[q]) * w;
        a1 += b2f(r1[q]) * w;
        a2 += b2f(r2[q]) * w;
        a3 += b2f(r3[q]) * w;
      }
    }
  } else {
    const float* x0 = (const float*)x + (long)row0 * FIN;
    const float* wp = (const float*)W1;
#pragma unroll 8
    for (int k = 0; k < FIN; ++k) {
      float w = wp[k * HID + lane];
      a0 += x0[k] * w;
      a1 += x0[FIN + k] * w;
      a2 += x0[2 * FIN + k] * w;
      a3 += x0[3 * FIN + k] * w;
    }
  }
  float d0 = rsqrtf((float)cnt[row0 + 0] + 1.0f);
  float d1 = rsqrtf((float)cnt[row0 + 1] + 1.0f);
  float d2 = rsqrtf((float)cnt[row0 + 2] + 1.0f);
  float d3 = rsqrtf((float)cnt[row0 + 3] + 1.0f);
  xw1[(long)(row0 + 0) * HID + lane] = a0 * d0;
  xw1[(long)(row0 + 1) * HID + lane] = a1 * d1;
  xw1[(long)(row0 + 2) * HID + lane] = a2 * d2;
  xw1[(long)(row0 + 3) * HID + lane] = a3 * d3;
}

// ---------- gather A: h1 = relu(Agg(sxw1)+b1); sxw2 = (h1 @ W2)*dinv -------
// Unconditional 8-wide gather batches: slot tail entries are sentinel NN,
// which indexes the phantom zero row (L1-hot, adds 0).
__global__ __launch_bounds__(256) void gatherA_kernel(const float* __restrict__ sxw,
                                                      const int* __restrict__ cnt,
                                                      const unsigned short* __restrict__ slot,
                                                      float* __restrict__ sxw2,
                                                      const void* __restrict__ b1v,
                                                      const void* __restrict__ W2,
                                                      const int* __restrict__ flags) {
  int n = blockIdx.x * 4 + (threadIdx.x >> 6);
  if (n >= NN) return;
  int fF = flags[0];
  int c = threadIdx.x & 63;
  float acc = sxw[(long)n * HID + c];           // self term (already * dinv[n])
  int m = cnt[n]; if (m > CAP) m = CAP;
  const unsigned short* sl = slot + (long)n * CAP;
  float accB = 0.f;
  for (int e0 = 0; e0 < m; e0 += 8) {
    us8 s8 = *(const us8*)(sl + e0);            // 8 ids, 16B
    acc  += sxw[(long)s8[0] * HID + c];
    accB += sxw[(long)s8[1] * HID + c];
    acc  += sxw[(long)s8[2] * HID + c];
    accB += sxw[(long)s8[3] * HID + c];
    acc  += sxw[(long)s8[4] * HID + c];
    accB += sxw[(long)s8[5] * HID + c];
    acc  += sxw[(long)s8[6] * HID + c];
    accB += sxw[(long)s8[7] * HID + c];
  }
  float dn = rsqrtf((float)cnt[n] + 1.0f);
  float h1 = (acc + accB) * dn + ldf(b1v, c, fF);
  h1 = h1 > 0.f ? h1 : 0.f;                     // relu'd hidden, channel c

  // xw2[n][c] = sum_k h1[k] * W2[k][c]  via 64 wave broadcasts; fold dinv[n]
  float o = 0.f;
#pragma unroll 8
  for (int k = 0; k < HID; ++k)
    o += __shfl(h1, k) * ldf(W2, k * HID + c, fF);
  sxw2[(long)n * HID + c] = o * dn;
}

// ---------- gather B: h2 = Agg(sxw2); n2 = ||h2+b2||^2 ----------
__global__ __launch_bounds__(256) void gatherB_kernel(const float* __restrict__ sxw,
                                                      const int* __restrict__ cnt,
                                                      const unsigned short* __restrict__ slot,
                                                      float* __restrict__ h,
                                                      float* __restrict__ n2,
                                                      const void* __restrict__ b2v,
                                                      const int* __restrict__ flags) {
  int n = blockIdx.x * 4 + (threadIdx.x >> 6);
  if (n >= NN) return;
  int c = threadIdx.x & 63;
  float acc = sxw[(long)n * HID + c];           // self term (already * dinv[n])
  int m = cnt[n]; if (m > CAP) m = CAP;
  const unsigned short* sl = slot + (long)n * CAP;
  float accB = 0.f;
  for (int e0 = 0; e0 < m; e0 += 8) {
    us8 s8 = *(const us8*)(sl + e0);
    acc  += sxw[(long)s8[0] * HID + c];
    accB += sxw[(long)s8[1] * HID + c];
    acc  += sxw[(long)s8[2] * HID + c];
    accB += sxw[(long)s8[3] * HID + c];
    acc  += sxw[(long)s8[4] * HID + c];
    accB += sxw[(long)s8[5] * HID + c];
    acc  += sxw[(long)s8[6] * HID + c];
    accB += sxw[(long)s8[7] * HID + c];
  }
  float dn = rsqrtf((float)cnt[n] + 1.0f);
  float h2 = (acc + accB) * dn;
  h[(long)n * HID + c] = h2;
  float v = h2 + ldf(b2v, c, flags[0]);
  float s = v * v;
  s += __shfl_xor(s, 1); s += __shfl_xor(s, 2); s += __shfl_xor(s, 4);
  s += __shfl_xor(s, 8); s += __shfl_xor(s, 16); s += __shfl_xor(s, 32);
  if (c == 0) n2[n] = s;
}

// ---------- FGW: 4 nodes/block, 8-lane octet per (node, template) ----------
#define NODES_PB 4
#define TPN 80            // threads per node (10 templates x 8 lanes)
#define XLP 65            // padded xl row stride

__global__ __launch_bounds__(320, 2) void fgw_kernel(
    const float* __restrict__ h2,        // [NN,64] fp32 ws (pre-b2)
    const void* __restrict__ b2v,
    const void* __restrict__ nbr_idx,
    const void* __restrict__ nbr_mask,
    const void* __restrict__ C_local,
    const void* __restrict__ tmpl,       // [10,8,8]
    const void* __restrict__ tfeat,      // [10,8,64]
    const void* __restrict__ Wlin,       // [74,6]
    const void* __restrict__ blin,       // [6]
    void* __restrict__ out,              // [NN,6]
    const int* __restrict__ flags,
    const float* __restrict__ tn2min,    // [11]: per-t mins + global min
    const float* __restrict__ n2)        // [NN] node norm^2
{
  const int tid = threadIdx.x;
  const int fF = flags[0];
  const int fI = flags[1];
  const int nb = tid / TPN;
  const int local = tid - nb * TPN;      // [0,80)
  const int t = local >> 3;
  const int j = local & 7;
  const int n = blockIdx.x * NODES_PB + nb;
  const int lane = tid & 63;
  const int ob = lane & 56;

  __shared__ float xlS[NODES_PB][LSZ][XLP];
  __shared__ float C1S[NODES_PB][81];
  __shared__ float hwS[NODES_PB][LSZ];
  __shared__ float f1S[NODES_PB][LSZ];
  __shared__ float xnS[NODES_PB][LSZ];
  __shared__ float distS[NODES_PB][NTPL];
  __shared__ float xmaxS[NODES_PB];
  __shared__ int   needS[NODES_PB];
  __shared__ int   sidxS[NODES_PB][LSZ];
  __shared__ float WlinS[(HID + NTPL) * NCLS + NCLS];   // Wlin + blin

  // stage epilogue weights once per block (coalesced-ish)
  for (int i = tid; i < (HID + NTPL) * NCLS; i += 320)
    WlinS[i] = ldf(Wlin, i, fF);
  if (tid < NCLS) WlinS[(HID + NTPL) * NCLS + tid] = ldf(blin, tid, fF);

  if (local < LSZ) {
    int idx = (local == 0) ? n : ldi(nbr_idx, (long)n * KNEI + local - 1, fI);
    sidxS[nb][local] = idx;
    xnS[nb][local] = n2[idx];
  }
  if (local < HID)
    xlS[nb][0][local] = h2[(long)n * HID + local] + ldf(b2v, local, fF);
  __syncthreads();   // B1

  if (local == 0) {
    float xm = xnS[nb][0];
#pragma unroll
    for (int l = 1; l < LSZ; ++l) xm = fmaxf(xm, xnS[nb][l]);
    xmaxS[nb] = xm;
    needS[nb] = ((sqrtf(tn2min[NTPL]) - sqrtf(xm)) >= 5.0990195f) ? 0 : 1;
  }
  __syncthreads();   // B2

  const int need = needS[nb];
  if (need) {
    for (int i = local; i < 8 * HID; i += TPN) {
      int l = 1 + (i >> 6), k = i & 63;
      xlS[nb][l][k] = h2[(long)sidxS[nb][l] * HID + k] + ldf(b2v, k, fF);
    }
    for (int i = local; i < 81; i += TPN)
      C1S[nb][i] = ldf(C_local, (long)n * 81 + i, fF);
  }
  __syncthreads();   // B3

  if (need && local < LSZ) {
    int l = local;
    float msum = 0.f, f1 = 0.f;
#pragma unroll
    for (int jj = 0; jj < LSZ; ++jj) {
      float mj = ldf(nbr_mask, (long)n * LSZ + jj, fF);
      msum += mj;
      float c = C1S[nb][l * LSZ + jj];
      f1 += c * c * mj;
    }
    float inv = frcp(msum);
    hwS[nb][l] = ldf(nbr_mask, (long)n * LSZ + l, fF) * inv;
    f1S[nb][l] = f1 * inv;
  }
  __syncthreads();   // B4

  bool slow = need && ((sqrtf(tn2min[t]) - sqrtf(xmaxS[nb])) < 5.0990195f);
  if (slow) {
    float C2c[NTN];
    float f2h2;
    {
      float s = 0.f;
#pragma unroll
      for (int m = 0; m < NTN; ++m) {
        C2c[m] = ldf(tmpl, t * 64 + m * 8 + j, fF);
        float r = ldf(tmpl, t * 64 + j * 8 + m, fF);
        s += r * r;
      }
      f2h2 = s * 0.125f;
    }
    float hwr[LSZ], f1r[LSZ];
#pragma unroll
    for (int l = 0; l < LSZ; ++l) { hwr[l] = hwS[nb][l]; f1r[l] = f1S[nb][l]; }

    float Mc[LSZ];
    {
      float accI[LSZ];
#pragma unroll
      for (int l = 0; l < LSZ; ++l) accI[l] = 0.f;
      float tn2 = 0.f;
      const long tb = (long)local * HID;
      for (int kb = 0; kb < 8; ++kb) {
        float r[8];
        if (!fF) {
          us8 v = *(const us8*)((const bf16_t*)tfeat + tb + kb * 8);
#pragma unroll
          for (int q = 0; q < 8; ++q) r[q] = b2f(v[q]);
        } else {
#pragma unroll
          for (int q = 0; q < 8; ++q) r[q] = ((const float*)tfeat)[tb + kb * 8 + q];
        }
#pragma unroll
        for (int q = 0; q < 8; ++q) tn2 += r[q] * r[q];
#pragma unroll
        for (int l = 0; l < LSZ; ++l) {
          float s = 0.f;
#pragma unroll
          for (int q = 0; q < 8; ++q) s += xlS[nb][l][kb * 8 + q] * r[q];
          accI[l] += s;
        }
      }
#pragma unroll
      for (int l = 0; l < LSZ; ++l)
        Mc[l] = xnS[nb][l] + tn2 - 2.f * accI[l];
    }

    float Tc[LSZ], Kc[LSZ], u[LSZ];
#pragma unroll
    for (int l = 0; l < LSZ; ++l) Tc[l] = hwr[l] * 0.125f;

    float v = 1.0f;
    for (int outer = 0; outer < 3; ++outer) {
      float Ac[LSZ];
#pragma unroll
      for (int l = 0; l < LSZ; ++l) {
        float s = 0.f;
#pragma unroll
        for (int l2 = 0; l2 < LSZ; ++l2) s += C1S[nb][l * LSZ + l2] * Tc[l2];
        Ac[l] = s;
      }
#pragma unroll
      for (int l = 0; l < LSZ; ++l) {
        float s = 0.f;
#pragma unroll
        for (int m = 0; m < NTN; ++m) s += __shfl(Ac[l], ob + m) * C2c[m];
        float tens = f1r[l] + f2h2 - 2.f * s;
        Kc[l] = __expf(-5.0f * (Mc[l] + tens));
      }
      v = 1.0f;
      for (int it = 0; it < 5; ++it) {
#pragma unroll
        for (int l = 0; l < LSZ; ++l) {
          float p = Kc[l] * v;
          p += __shfl_xor(p, 1); p += __shfl_xor(p, 2); p += __shfl_xor(p, 4);
          u[l] = hwr[l] * frcp(p + 1e-16f);
        }
        float s = 0.f;
#pragma unroll
        for (int l = 0; l < LSZ; ++l) s += Kc[l] * u[l];
        v = 0.125f * frcp(s + 1e-16f);
      }
#pragma unroll
      for (int l = 0; l < LSZ; ++l) Tc[l] = u[l] * Kc[l] * v;
    }
    {
      float Ac[LSZ];
#pragma unroll
      for (int l = 0; l < LSZ; ++l) {
        float s = 0.f;
#pragma unroll
        for (int l2 = 0; l2 < LSZ; ++l2) s += C1S[nb][l * LSZ + l2] * Tc[l2];
        Ac[l] = s;
      }
      float cl = 0.f;
#pragma unroll
      for (int l = 0; l < LSZ; ++l) {
        float s = 0.f;
#pragma unroll
        for (int m = 0; m < NTN; ++m) s += __shfl(Ac[l], ob + m) * C2c[m];
        float tens = f1r[l] + f2h2 - 2.f * s;
        cl += Tc[l] * 0.5f * (Mc[l] + tens);
      }
      cl += __shfl_xor(cl, 1); cl += __shfl_xor(cl, 2); cl += __shfl_xor(cl, 4);
      if (j == 0) distS[nb][t] = cl;
    }
  } else if (j == 0) {
    distS[nb][t] = 0.f;
  }
  __syncthreads();   // B5

  if (local < NCLS) {
    int c = local;
    float acc = WlinS[(HID + NTPL) * NCLS + c];
#pragma unroll
    for (int k = 0; k < HID; ++k)
      acc += xlS[nb][0][k] * WlinS[k * NCLS + c];
#pragma unroll
    for (int tt = 0; tt < NTPL; ++tt)
      acc += distS[nb][tt] * WlinS[(HID + tt) * NCLS + c];
    float r = acc > 0.f ? acc : 0.f;
    if (fF) ((float*)out)[(long)n * NCLS + c] = r;
    else    ((bf16_t*)out)[(long)n * NCLS + c] = f2b(r);
  }
}

extern "C" void kernel_launch(void* const* d_in, const int* in_sizes, int n_in,
                              void* d_out, int out_size, void* d_ws, size_t ws_size,
                              hipStream_t stream) {
  (void)in_sizes; (void)n_in; (void)out_size; (void)ws_size;
  const void* x     = d_in[0];
  const void* ei    = d_in[1];
  const void* nbr   = d_in[2];
  const void* nmask = d_in[3];
  const void* Cl    = d_in[4];
  const void* W1    = d_in[5];
  const void* b1    = d_in[6];
  const void* W2    = d_in[7];
  const void* b2    = d_in[8];
  const void* tmpl  = d_in[9];
  const void* tfeat = d_in[10];
  const void* Wlin  = d_in[11];
  const void* blin  = d_in[12];

  // ws layout (4B words): flags[4] | tn2min[12] | n2 NN | pos NN |
  //   slot16 (CAP*NN/2 words) | bufA 64*(NN+1) | bufB 64*(NN+1)
  // bufA/bufB row NN is the phantom zero row for sentinel gathers.
  int*            flags  = (int*)d_ws;
  float*          tn2min = (float*)d_ws + 4;
  float*          n2     = (float*)d_ws + 16;
  int*            pos    = (int*)(n2 + NN);
  unsigned short* slot   = (unsigned short*)(pos + NN);
  float*          bufA   = (float*)((int*)(pos + NN) + (long)CAP * NN / 2);
  float*          bufB   = bufA + (long)(NN + 1) * HID;

  // probe + pos zero + slot sentinel fill + phantom zero rows
  probe_kernel<<<512, 256, 0, stream>>>(x, ei, tfeat, flags, tn2min, pos,
                                        slot, bufA, bufB);
  scatter_kernel<<<(EE + 255) / 256, 256, 0, stream>>>(ei, pos, slot, flags);

  // layer 1 GEMM (scalar R5 form) + dinv fold
  gemm1_kernel<<<NN / 16, 256, 0, stream>>>(x, W1, pos, bufA, flags);
  // gather A: sum sxw1 rows -> relu(h1) -> in-wave GEMV W2 -> sxw2 (bufB)
  gatherA_kernel<<<NN / 4, 256, 0, stream>>>(bufA, pos, slot, bufB, b1, W2, flags);
  // gather B: sum sxw2 rows -> h2 (bufA) + n2
  gatherB_kernel<<<NN / 4, 256, 0, stream>>>(bufB, pos, slot, bufA, n2, b2, flags);

  fgw_kernel<<<NN / NODES_PB, 320, 0, stream>>>(bufA, b2, nbr, nmask, Cl, tmpl,
                                                tfeat, Wlin, blin, d_out, flags,
                                                tn2min, n2);
}